// Round 26
// baseline (43.286 us; speedup 1.0000x reference)
//
#include <hip/hip_runtime.h>

// Problem constants (match reference)
#define B_SZ   2
#define T_CTX  1024
#define E_IN   256
#define D_QK   64
#define DV_OUT 64
#define NROWS  (B_SZ * T_CTX)
#define RPB    4                   // rows per proj block (one per wave)
#define QT     4                   // queries per attn tile
#define CH     128                 // j-chunk per attn block (= block threads)

// r26 = r22 with ONE change: attn stages its 32KB kpt chunk into LDS via a
// dependency-free copy burst (16 independent float4 loads/thread -> single
// latency exposure), then the score loop reads LDS at ~5cy instead of
// paying 8 serialized ~250cy L2 rounds. Owner-aligned XCD swizzle kept
// (staging reads come from the local L2). proj/finalize verbatim.

// ---------------------------------------------------------------------------
// Kernel 1: projections (r22 VERBATIM). Grid 512 = 8 XCDs x 64 slots;
// owner xcd covers chunks {kk, 7-kk} of batch b (kk=xcd&3, b=xcd>>2).
// Also zeroes this block's rows of outacc/lacc (replay determinism).
// ---------------------------------------------------------------------------
__global__ __launch_bounds__(256) void proj_kernel(
    const float* __restrict__ x,
    const float* __restrict__ Wq, const float* __restrict__ bq,
    const float* __restrict__ Wk, const float* __restrict__ bk,
    const float* __restrict__ Wv, const float* __restrict__ bv,
    const float* __restrict__ W1, const float* __restrict__ b1,
    float* __restrict__ qpb, float* __restrict__ kpt, float* __restrict__ v,
    float* __restrict__ outacc, float* __restrict__ lacc)
{
    __shared__ float xs[RPB * E_IN];
    __shared__ float qs[RPB * D_QK];
    __shared__ float ks[RPB * D_QK];
    __shared__ float kps[RPB * D_QK];

    // ---- owner-aligned decode: P%8 = XCD = owner ----
    const int P   = blockIdx.x;
    const int xcd = P & 7;
    const int slt = P >> 3;                // 0..63
    const int bb  = xcd >> 2;
    const int kk  = xcd & 3;
    const int row0 = (slt < 32)
        ? bb * T_CTX + kk * 128 + slt * 4
        : bb * T_CTX + (7 - kk) * 128 + (slt - 32) * 4;

    const int t = threadIdx.x;

    // zero the atomic accumulators for this block's rows (every launch)
    outacc[(size_t)row0 * DV_OUT + t] = 0.f;
    if (t < RPB) lacc[row0 + t] = 0.f;

    *(float4*)&xs[4 * t] = *(const float4*)&x[(size_t)row0 * E_IN + 4 * t];
    __syncthreads();

    const int d = t & 63;
    const int r = t >> 6;                  // wave -> row (0..3)
    const float* xrow = &xs[r * E_IN];

    float aq0 = 0.f, aq1 = 0.f, ak0 = 0.f, ak1 = 0.f, av0 = 0.f, av1 = 0.f;
    #pragma unroll 8
    for (int e = 0; e < E_IN; e += 2) {
        float x0 = xrow[e], x1 = xrow[e + 1];
        aq0 += x0 * Wq[(e)     * D_QK   + d];
        aq1 += x1 * Wq[(e + 1) * D_QK   + d];
        ak0 += x0 * Wk[(e)     * D_QK   + d];
        ak1 += x1 * Wk[(e + 1) * D_QK   + d];
        av0 += x0 * Wv[(e)     * DV_OUT + d];
        av1 += x1 * Wv[(e + 1) * DV_OUT + d];
    }
    qs[r * D_QK + d] = fmaxf(aq0 + aq1 + bq[d], 0.f);
    ks[r * D_QK + d] = fmaxf(ak0 + ak1 + bk[d], 0.f);
    v[(size_t)(row0 + r) * DV_OUT + d] = av0 + av1 + bv[d];
    __syncthreads();

    const float* qrow = &qs[r * D_QK];
    const float* krow = &ks[r * D_QK];
    float ap0 = 0.f, ap1 = 0.f, bp0 = 0.f, bp1 = 0.f;
    #pragma unroll 8
    for (int e = 0; e < D_QK; e += 2) {
        ap0 += qrow[e]     * W1[(e)            * D_QK + d];
        ap1 += qrow[e + 1] * W1[(e + 1)        * D_QK + d];
        bp0 += krow[e]     * W1[(D_QK + e)     * D_QK + d];
        bp1 += krow[e + 1] * W1[(D_QK + e + 1) * D_QK + d];
    }
    qpb[(size_t)(row0 + r) * D_QK + d] = ap0 + ap1 + b1[d];
    kps[r * D_QK + d] = bp0 + bp1;
    __syncthreads();

    if (t < D_QK) {                        // transposed kp write (4 rows)
        float4 kq = make_float4(kps[0 * D_QK + t], kps[1 * D_QK + t],
                                kps[2 * D_QK + t], kps[3 * D_QK + t]);
        *(float4*)&kpt[(size_t)t * NROWS + row0] = kq;
    }
}

// ---------------------------------------------------------------------------
// Kernel 2: partial attention with LDS-STAGED kpt chunk.
// Grid 2304 = 8 XCDs x 288 slots, owner-aligned decode (r22). 128 thr.
// Staging: 16 independent float4 loads/thread (32KB chunk), single
// latency exposure, owner-local L2. Score loop reads kls (conflict-free:
// lane t -> bank t%32). PV unchanged (global float2 v loads).
// LDS ~37.4KB -> 4 blocks/CU (8 waves).
// ---------------------------------------------------------------------------
__global__ __launch_bounds__(128) void attn_kernel(
    const float* __restrict__ qpb, const float* __restrict__ kpt,
    const float* __restrict__ v,
    const float* __restrict__ W2, const float* __restrict__ b2,
    float* __restrict__ outacc, float* __restrict__ lacc)
{
    __shared__ float kls[D_QK * CH];        // 32 KB: kls[dd*128 + j]
    __shared__ float qqT[D_QK][QT];         // [d][q] 1 KB
    __shared__ float w2s[D_QK];
    __shared__ float pT[CH][QT];            // [j][q] 2 KB (transposed)
    __shared__ float redl[2][QT];
    __shared__ float part[2][QT][DV_OUT];   // 2 KB

    // ---- owner-aligned decode: P%8 = XCD = owner ----
    const int P   = blockIdx.x;
    const int xcd = P & 7;
    const int slt = P >> 3;                // 0..287
    const int b   = xcd >> 2;
    const int kk  = xcd & 3;
    const int n1  = 256 - 32 * kk;         // blocks for chunk kk
    int tile, chunk;
    if (slt < n1) { chunk = kk;     tile = 32 * kk + slt; }
    else          { chunk = 7 - kk; tile = 32 * (7 - kk) + (slt - n1); }
    const int i0 = tile * QT;
    const int jc = chunk * CH;

    const int t    = threadIdx.x;           // 0..127
    const int lane = t & 63;
    const int wv   = t >> 6;                // 0..1
    const size_t base = (size_t)b * T_CTX;

    // ---- stage kpt chunk: 2048 float4, 16 per thread, all independent ----
    {
        const float* ksrc = kpt + base + jc;
        #pragma unroll
        for (int k = 0; k < 16; ++k) {
            const int f   = t + 128 * k;    // float4 index 0..2047
            const int dd  = f >> 5;         // row (d)
            const int col = (f & 31) * 4;   // j offset
            float4 val = *(const float4*)(ksrc + (size_t)dd * NROWS + col);
            *(float4*)&kls[dd * CH + col] = val;
        }
    }
    // ---- stage q-tile (transposed) + w2 ----
    #pragma unroll
    for (int kq = t; kq < QT * D_QK; kq += 128) {
        const int q = kq >> 6, d = kq & 63;
        qqT[d][q] = qpb[(base + i0 + q) * D_QK + d];
    }
    if (t < D_QK) w2s[t] = W2[t];
    __syncthreads();

    const float bias2 = b2[0];
    const int j = jc + t;                   // this thread's j

    float acc[QT];
    #pragma unroll
    for (int q = 0; q < QT; ++q) acc[q] = 0.f;

    #pragma unroll 8
    for (int dd = 0; dd < D_QK; ++dd) {
        float kv  = kls[dd * CH + t];       // LDS, conflict-free
        float4 qa = *(const float4*)&qqT[dd][0];
        float wd  = w2s[dd];
        acc[0] += fmaxf(qa.x + kv, 0.f) * wd;
        acc[1] += fmaxf(qa.y + kv, 0.f) * wd;
        acc[2] += fmaxf(qa.z + kv, 0.f) * wd;
        acc[3] += fmaxf(qa.w + kv, 0.f) * wd;
    }

    // ---- per-thread exp + mask + single b128 pT store ----
    const int rel = j - i0;                 // valid iff rel <= q
    float p[QT];
    #pragma unroll
    for (int q = 0; q < QT; ++q)
        p[q] = (rel <= q) ? __expf(bias2 + acc[q]) : 0.f;
    *(float4*)&pT[t][0] = make_float4(p[0], p[1], p[2], p[3]);

    // ---- l reduce -> atomic ----
    #pragma unroll
    for (int q = 0; q < QT; ++q) {
        float lq = p[q];
        #pragma unroll
        for (int o = 32; o > 0; o >>= 1) lq += __shfl_xor(lq, o, 64);
        if (lane == 0) redl[wv][q] = lq;
    }
    __syncthreads();
    if (t < QT) atomicAdd(&lacc[base + i0 + t], redl[0][t] + redl[1][t]);

    // ---- PV: half-wave j-split, float2 v loads, b128 pT broadcasts ----
    const int half = lane >> 5;             // j parity within pair
    const int dp   = (lane & 31) * 2;       // dv pair
    float2 av2[QT];
    #pragma unroll
    for (int q = 0; q < QT; ++q) av2[q] = make_float2(0.f, 0.f);

    const float* vb = v + (base + jc + 64 * wv) * DV_OUT + dp;
    #pragma unroll 8
    for (int jj = 0; jj < 64; jj += 2) {
        const int jl = 64 * wv + jj + half;
        float2 vv2 = *(const float2*)(vb + (size_t)(jj + half) * DV_OUT);
        float4 pj  = *(const float4*)&pT[jl][0];   // 2 addrs/wave: free
        av2[0].x += pj.x * vv2.x; av2[0].y += pj.x * vv2.y;
        av2[1].x += pj.y * vv2.x; av2[1].y += pj.y * vv2.y;
        av2[2].x += pj.z * vv2.x; av2[2].y += pj.z * vv2.y;
        av2[3].x += pj.w * vv2.x; av2[3].y += pj.w * vv2.y;
    }
    #pragma unroll
    for (int q = 0; q < QT; ++q) {
        av2[q].x += __shfl_xor(av2[q].x, 32, 64);
        av2[q].y += __shfl_xor(av2[q].y, 32, 64);
    }
    if (half == 0) {
        #pragma unroll
        for (int q = 0; q < QT; ++q)
            *(float2*)&part[wv][q][dp] = av2[q];
    }
    __syncthreads();

    // ---- fold 2 waves + atomicAdd pv partials (2 per thread) ----
    #pragma unroll
    for (int kq = t; kq < QT * DV_OUT; kq += 128) {
        const int q = kq >> 6, dv = kq & 63;
        atomicAdd(&outacc[(base + i0 + q) * DV_OUT + dv],
                  part[0][q][dv] + part[1][q][dv]);
    }
}

// ---------------------------------------------------------------------------
// Kernel 3: finalize = divide. 256 blocks x 512 thr, coalesced. (UNCHANGED)
// ---------------------------------------------------------------------------
__global__ __launch_bounds__(512) void finalize_kernel(
    const float* __restrict__ outacc, const float* __restrict__ lacc,
    float* __restrict__ out)
{
    const size_t idx = (size_t)blockIdx.x * 512 + threadIdx.x;
    out[idx] = outacc[idx] / lacc[idx >> 6];
}

extern "C" void kernel_launch(void* const* d_in, const int* in_sizes, int n_in,
                              void* d_out, int out_size, void* d_ws, size_t ws_size,
                              hipStream_t stream) {
    const float* x  = (const float*)d_in[0];
    const float* Wq = (const float*)d_in[1];
    const float* bq = (const float*)d_in[2];
    const float* Wk = (const float*)d_in[3];
    const float* bk = (const float*)d_in[4];
    const float* Wv = (const float*)d_in[5];
    const float* bv = (const float*)d_in[6];
    const float* W1 = (const float*)d_in[7];
    const float* b1 = (const float*)d_in[8];
    const float* W2 = (const float*)d_in[9];
    const float* b2 = (const float*)d_in[10];
    float* out = (float*)d_out;

    float* ws     = (float*)d_ws;
    float* qpb    = ws;                                  // NROWS*64
    float* kpt    = ws + (size_t)NROWS * D_QK;           // 64*NROWS (transposed)
    float* vv     = ws + (size_t)2 * NROWS * D_QK;       // NROWS*64
    float* outacc = ws + (size_t)3 * NROWS * D_QK;       // NROWS*64
    float* lacc   = ws + (size_t)4 * NROWS * D_QK;       // NROWS

    proj_kernel<<<NROWS / RPB, 256, 0, stream>>>(x, Wq, bq, Wk, bk, Wv, bv,
                                                 W1, b1, qpb, kpt, vv,
                                                 outacc, lacc);
    attn_kernel<<<2304, CH, 0, stream>>>(qpb, kpt, vv, W2, b2, outacc, lacc);
    finalize_kernel<<<(NROWS * DV_OUT) / 512, 512, 0, stream>>>(outacc, lacc,
                                                                out);
}

// Round 27
// 36.558 us; speedup vs baseline: 1.1840x; 1.1840x over previous
//
#include <hip/hip_runtime.h>

// Problem constants (match reference)
#define B_SZ   2
#define T_CTX  1024
#define E_IN   256
#define D_QK   64
#define DV_OUT 64
#define NROWS  (B_SZ * T_CTX)
#define RPB    4                   // rows per proj block (one per wave)
#define QT     4                   // queries per attn tile
#define CH     128                 // j-chunk per attn block (= block threads)

// FINAL = r22 (measured best, reproduced: 36.64 / 36.62 us).
// Structure: proj (owner-swizzled) -> attn (QT=4, fold-free scores, lean PV,
// atomic epilogue, owner-swizzled) -> finalize (divide).
// XCD-owner-aligned swizzle: owner xcd = 4b + kk owns j-chunk pair
// {kk, 7-kk} of batch b; proj WRITERS and attn READERS of those kpt/v rows
// both run on the owner XCD -> local-L2 hits instead of Infinity-Cache.
// Exhausted levers (all neutral/negative vs this): occupancy x2, ILP x2,
// DS-diet, instr-diet, QT=8, kpt LDS-staging, spin-fused finalize,
// 4 proj restructures, software pipelining, threadfence combine.

// ---------------------------------------------------------------------------
// Kernel 1: projections. Grid 512 = 8 XCDs x 64 slots; owner xcd covers
// chunks {kk, 7-kk} of batch b (kk=xcd&3, b=xcd>>2).
// Also zeroes this block's rows of outacc/lacc (replay determinism).
// ---------------------------------------------------------------------------
__global__ __launch_bounds__(256) void proj_kernel(
    const float* __restrict__ x,
    const float* __restrict__ Wq, const float* __restrict__ bq,
    const float* __restrict__ Wk, const float* __restrict__ bk,
    const float* __restrict__ Wv, const float* __restrict__ bv,
    const float* __restrict__ W1, const float* __restrict__ b1,
    float* __restrict__ qpb, float* __restrict__ kpt, float* __restrict__ v,
    float* __restrict__ outacc, float* __restrict__ lacc)
{
    __shared__ float xs[RPB * E_IN];
    __shared__ float qs[RPB * D_QK];
    __shared__ float ks[RPB * D_QK];
    __shared__ float kps[RPB * D_QK];

    // ---- owner-aligned decode: P%8 = XCD = owner ----
    const int P   = blockIdx.x;
    const int xcd = P & 7;
    const int slt = P >> 3;                // 0..63
    const int bb  = xcd >> 2;
    const int kk  = xcd & 3;
    const int row0 = (slt < 32)
        ? bb * T_CTX + kk * 128 + slt * 4
        : bb * T_CTX + (7 - kk) * 128 + (slt - 32) * 4;

    const int t = threadIdx.x;

    // zero the atomic accumulators for this block's rows (every launch)
    outacc[(size_t)row0 * DV_OUT + t] = 0.f;
    if (t < RPB) lacc[row0 + t] = 0.f;

    *(float4*)&xs[4 * t] = *(const float4*)&x[(size_t)row0 * E_IN + 4 * t];
    __syncthreads();

    const int d = t & 63;
    const int r = t >> 6;                  // wave -> row (0..3)
    const float* xrow = &xs[r * E_IN];

    float aq0 = 0.f, aq1 = 0.f, ak0 = 0.f, ak1 = 0.f, av0 = 0.f, av1 = 0.f;
    #pragma unroll 8
    for (int e = 0; e < E_IN; e += 2) {
        float x0 = xrow[e], x1 = xrow[e + 1];
        aq0 += x0 * Wq[(e)     * D_QK   + d];
        aq1 += x1 * Wq[(e + 1) * D_QK   + d];
        ak0 += x0 * Wk[(e)     * D_QK   + d];
        ak1 += x1 * Wk[(e + 1) * D_QK   + d];
        av0 += x0 * Wv[(e)     * DV_OUT + d];
        av1 += x1 * Wv[(e + 1) * DV_OUT + d];
    }
    qs[r * D_QK + d] = fmaxf(aq0 + aq1 + bq[d], 0.f);
    ks[r * D_QK + d] = fmaxf(ak0 + ak1 + bk[d], 0.f);
    v[(size_t)(row0 + r) * DV_OUT + d] = av0 + av1 + bv[d];
    __syncthreads();

    const float* qrow = &qs[r * D_QK];
    const float* krow = &ks[r * D_QK];
    float ap0 = 0.f, ap1 = 0.f, bp0 = 0.f, bp1 = 0.f;
    #pragma unroll 8
    for (int e = 0; e < D_QK; e += 2) {
        ap0 += qrow[e]     * W1[(e)            * D_QK + d];
        ap1 += qrow[e + 1] * W1[(e + 1)        * D_QK + d];
        bp0 += krow[e]     * W1[(D_QK + e)     * D_QK + d];
        bp1 += krow[e + 1] * W1[(D_QK + e + 1) * D_QK + d];
    }
    qpb[(size_t)(row0 + r) * D_QK + d] = ap0 + ap1 + b1[d];
    kps[r * D_QK + d] = bp0 + bp1;
    __syncthreads();

    if (t < D_QK) {                        // transposed kp write (4 rows)
        float4 kq = make_float4(kps[0 * D_QK + t], kps[1 * D_QK + t],
                                kps[2 * D_QK + t], kps[3 * D_QK + t]);
        *(float4*)&kpt[(size_t)t * NROWS + row0] = kq;
    }
}

// ---------------------------------------------------------------------------
// Kernel 2: partial attention. Grid 2304 = 8 XCDs x 288 slots. Owner xcd
// serves chunk kk (tiles 32kk..255) then chunk 7-kk of batch b -- the
// chunks whose kpt/v rows it wrote in proj. QT=4, fold-free scores, lean
// PV, atomic epilogue into lacc/outacc.
// ---------------------------------------------------------------------------
__global__ __launch_bounds__(128) void attn_kernel(
    const float* __restrict__ qpb, const float* __restrict__ kpt,
    const float* __restrict__ v,
    const float* __restrict__ W2, const float* __restrict__ b2,
    float* __restrict__ outacc, float* __restrict__ lacc)
{
    __shared__ float qqT[D_QK][QT];         // [d][q] 1 KB
    __shared__ float w2s[D_QK];
    __shared__ float pT[CH][QT];            // [j][q] 2 KB (transposed)
    __shared__ float redl[2][QT];
    __shared__ float part[2][QT][DV_OUT];   // 2 KB

    // ---- owner-aligned decode: P%8 = XCD = owner ----
    const int P   = blockIdx.x;
    const int xcd = P & 7;
    const int slt = P >> 3;                // 0..287
    const int b   = xcd >> 2;
    const int kk  = xcd & 3;
    const int n1  = 256 - 32 * kk;         // blocks for chunk kk
    int tile, chunk;
    if (slt < n1) { chunk = kk;     tile = 32 * kk + slt; }
    else          { chunk = 7 - kk; tile = 32 * (7 - kk) + (slt - n1); }
    const int i0 = tile * QT;
    const int jc = chunk * CH;

    const int t    = threadIdx.x;           // 0..127
    const int lane = t & 63;
    const int wv   = t >> 6;                // 0..1
    const size_t base = (size_t)b * T_CTX;

    // ---- stage q-tile (transposed) + w2 ----
    #pragma unroll
    for (int kq = t; kq < QT * D_QK; kq += 128) {
        const int q = kq >> 6, d = kq & 63;
        qqT[d][q] = qpb[(base + i0 + q) * D_QK + d];
    }
    if (t < D_QK) w2s[t] = W2[t];
    __syncthreads();

    const float bias2 = b2[0];
    const int j = jc + t;                   // this thread's j
    const float* kb = kpt + base + j;       // stride NROWS per d

    float acc[QT];
    #pragma unroll
    for (int q = 0; q < QT; ++q) acc[q] = 0.f;

    #pragma unroll 8
    for (int dd = 0; dd < D_QK; ++dd) {
        float kv  = kb[(size_t)dd * NROWS];
        float4 qa = *(const float4*)&qqT[dd][0];
        float wd  = w2s[dd];
        acc[0] += fmaxf(qa.x + kv, 0.f) * wd;
        acc[1] += fmaxf(qa.y + kv, 0.f) * wd;
        acc[2] += fmaxf(qa.z + kv, 0.f) * wd;
        acc[3] += fmaxf(qa.w + kv, 0.f) * wd;
    }

    // ---- per-thread exp + mask + single b128 pT store ----
    const int rel = j - i0;                 // valid iff rel <= q
    float p[QT];
    #pragma unroll
    for (int q = 0; q < QT; ++q)
        p[q] = (rel <= q) ? __expf(bias2 + acc[q]) : 0.f;
    *(float4*)&pT[t][0] = make_float4(p[0], p[1], p[2], p[3]);

    // ---- l reduce -> atomic ----
    #pragma unroll
    for (int q = 0; q < QT; ++q) {
        float lq = p[q];
        #pragma unroll
        for (int o = 32; o > 0; o >>= 1) lq += __shfl_xor(lq, o, 64);
        if (lane == 0) redl[wv][q] = lq;
    }
    __syncthreads();
    if (t < QT) atomicAdd(&lacc[base + i0 + t], redl[0][t] + redl[1][t]);

    // ---- PV: half-wave j-split, float2 v loads, b128 pT broadcasts ----
    const int half = lane >> 5;             // j parity within pair
    const int dp   = (lane & 31) * 2;       // dv pair
    float2 av2[QT];
    #pragma unroll
    for (int q = 0; q < QT; ++q) av2[q] = make_float2(0.f, 0.f);

    const float* vb = v + (base + jc + 64 * wv) * DV_OUT + dp;
    #pragma unroll 8
    for (int jj = 0; jj < 64; jj += 2) {
        const int jl = 64 * wv + jj + half;
        float2 vv2 = *(const float2*)(vb + (size_t)(jj + half) * DV_OUT);
        float4 pj  = *(const float4*)&pT[jl][0];   // 2 addrs/wave: free
        av2[0].x += pj.x * vv2.x; av2[0].y += pj.x * vv2.y;
        av2[1].x += pj.y * vv2.x; av2[1].y += pj.y * vv2.y;
        av2[2].x += pj.z * vv2.x; av2[2].y += pj.z * vv2.y;
        av2[3].x += pj.w * vv2.x; av2[3].y += pj.w * vv2.y;
    }
    #pragma unroll
    for (int q = 0; q < QT; ++q) {
        av2[q].x += __shfl_xor(av2[q].x, 32, 64);
        av2[q].y += __shfl_xor(av2[q].y, 32, 64);
    }
    if (half == 0) {
        #pragma unroll
        for (int q = 0; q < QT; ++q)
            *(float2*)&part[wv][q][dp] = av2[q];
    }
    __syncthreads();

    // ---- fold 2 waves + atomicAdd pv partials (2 per thread) ----
    #pragma unroll
    for (int kq = t; kq < QT * DV_OUT; kq += 128) {
        const int q = kq >> 6, dv = kq & 63;
        atomicAdd(&outacc[(base + i0 + q) * DV_OUT + dv],
                  part[0][q][dv] + part[1][q][dv]);
    }
}

// ---------------------------------------------------------------------------
// Kernel 3: finalize = divide. 256 blocks x 512 thr, coalesced.
// ---------------------------------------------------------------------------
__global__ __launch_bounds__(512) void finalize_kernel(
    const float* __restrict__ outacc, const float* __restrict__ lacc,
    float* __restrict__ out)
{
    const size_t idx = (size_t)blockIdx.x * 512 + threadIdx.x;
    out[idx] = outacc[idx] / lacc[idx >> 6];
}

extern "C" void kernel_launch(void* const* d_in, const int* in_sizes, int n_in,
                              void* d_out, int out_size, void* d_ws, size_t ws_size,
                              hipStream_t stream) {
    const float* x  = (const float*)d_in[0];
    const float* Wq = (const float*)d_in[1];
    const float* bq = (const float*)d_in[2];
    const float* Wk = (const float*)d_in[3];
    const float* bk = (const float*)d_in[4];
    const float* Wv = (const float*)d_in[5];
    const float* bv = (const float*)d_in[6];
    const float* W1 = (const float*)d_in[7];
    const float* b1 = (const float*)d_in[8];
    const float* W2 = (const float*)d_in[9];
    const float* b2 = (const float*)d_in[10];
    float* out = (float*)d_out;

    float* ws     = (float*)d_ws;
    float* qpb    = ws;                                  // NROWS*64
    float* kpt    = ws + (size_t)NROWS * D_QK;           // 64*NROWS (transposed)
    float* vv     = ws + (size_t)2 * NROWS * D_QK;       // NROWS*64
    float* outacc = ws + (size_t)3 * NROWS * D_QK;       // NROWS*64
    float* lacc   = ws + (size_t)4 * NROWS * D_QK;       // NROWS

    proj_kernel<<<NROWS / RPB, 256, 0, stream>>>(x, Wq, bq, Wk, bk, Wv, bv,
                                                 W1, b1, qpb, kpt, vv,
                                                 outacc, lacc);
    attn_kernel<<<2304, CH, 0, stream>>>(qpb, kpt, vv, W2, b2, outacc, lacc);
    finalize_kernel<<<(NROWS * DV_OUT) / 512, 512, 0, stream>>>(outacc, lacc,
                                                                out);
}